// Round 11
// baseline (216.258 us; speedup 1.0000x reference)
//
#include <hip/hip_runtime.h>
#include <hip/hip_bf16.h>

#define N_NODES 50000
#define N_EDGES 1000000
#define DIM 64
#define N_GRAPHS 64
#define OUT_DIM 8
#define NBLK_SCAN 196         // ceil(50000/256)
#define NPART 8               // one dst-range partition per XCD
#define PARTBLK 128           // per-partition blocks (count_local / fill_local)
#define NODES_PER_PART (N_NODES / NPART)   // 6250
#define NB_RP 512             // chunked radix-partition blocks
#define CHUNK_E4 489          // ceil(250000/512)
#define B_STRIDE 8192         // bf16 elements per packed weight layer (128x64)

typedef __attribute__((ext_vector_type(8))) short short8;   // 8 bf16 = 4 VGPR
typedef __attribute__((ext_vector_type(4))) float f32x4;    // MFMA C/D
typedef __attribute__((ext_vector_type(4))) int v4i;

__device__ __forceinline__ unsigned short f2b(float f) {
    __hip_bfloat16 h = __float2bfloat16(f);
    return *reinterpret_cast<unsigned short*>(&h);
}
__device__ __forceinline__ float b2f(unsigned short u) {
    __hip_bfloat16 h = *reinterpret_cast<__hip_bfloat16*>(&u);
    return __bfloat162float(h);
}

// ---------------------------------------------------------------------------
// histB: per-chunk 8-bucket counts ONLY (no cnt atomics — R10's histA paid
// 31 MB of HBM writes ping-ponging cnt lines across XCDs). Bucket counts in
// VGPRs (static if-chain), wave shfl-reduce, LDS combine.
// ---------------------------------------------------------------------------
__global__ void histB_kernel(const int* __restrict__ dst, int* __restrict__ blockcnt) {
    __shared__ int sc[NPART];
    if (threadIdx.x < NPART) sc[threadIdx.x] = 0;
    __syncthreads();

    int e4lo = blockIdx.x * CHUNK_E4;
    int e4hi = e4lo + CHUNK_E4; if (e4hi > N_EDGES / 4) e4hi = N_EDGES / 4;

    int c0 = 0, c1 = 0, c2 = 0, c3 = 0, c4 = 0, c5 = 0, c6 = 0, c7 = 0;
    for (int e4 = e4lo + threadIdx.x; e4 < e4hi; e4 += 256) {
        v4i d = ((const v4i*)dst)[e4];
#define CNT1(DD)                                                              \
        {                                                                     \
            unsigned p = (unsigned)(DD) / NODES_PER_PART;                     \
            c0 += (p == 0); c1 += (p == 1); c2 += (p == 2); c3 += (p == 3);   \
            c4 += (p == 4); c5 += (p == 5); c6 += (p == 6); c7 += (p == 7);   \
        }
        CNT1(d.x) CNT1(d.y) CNT1(d.z) CNT1(d.w)
#undef CNT1
    }
    #pragma unroll
    for (int off = 32; off > 0; off >>= 1) {
        c0 += __shfl_xor(c0, off); c1 += __shfl_xor(c1, off);
        c2 += __shfl_xor(c2, off); c3 += __shfl_xor(c3, off);
        c4 += __shfl_xor(c4, off); c5 += __shfl_xor(c5, off);
        c6 += __shfl_xor(c6, off); c7 += __shfl_xor(c7, off);
    }
    if ((threadIdx.x & 63) == 0) {
        atomicAdd(&sc[0], c0); atomicAdd(&sc[1], c1);
        atomicAdd(&sc[2], c2); atomicAdd(&sc[3], c3);
        atomicAdd(&sc[4], c4); atomicAdd(&sc[5], c5);
        atomicAdd(&sc[6], c6); atomicAdd(&sc[7], c7);
    }
    __syncthreads();
    if (threadIdx.x < NPART) blockcnt[blockIdx.x * NPART + threadIdx.x] = sc[threadIdx.x];
}

// ---------------------------------------------------------------------------
// scan8: exclusive scan over blockcnt in bucket-major order (e = p*NB_RP+b).
// abs_off[e] = bucketed-array offset for (bucket p, chunk-block b).
// bucket_base[p] = abs_off[p*NB_RP]; bucket_base[8] = N_EDGES.
// ---------------------------------------------------------------------------
__global__ void scan8_kernel(const int* __restrict__ blockcnt,
                             int* __restrict__ abs_off, int* __restrict__ bucket_base) {
    __shared__ int part[1024];
    int t = threadIdx.x;
    int v[4], s = 0;
    #pragma unroll
    for (int i = 0; i < 4; ++i) {
        int e = 4 * t + i;
        int p = e >> 9, b = e & (NB_RP - 1);
        v[i] = blockcnt[b * NPART + p];
        s += v[i];
    }
    part[t] = s;
    __syncthreads();
    for (int off = 1; off < 1024; off <<= 1) {
        int u = (t >= off) ? part[t - off] : 0;
        __syncthreads();
        part[t] += u;
        __syncthreads();
    }
    int base = (t == 0) ? 0 : part[t - 1];
    #pragma unroll
    for (int i = 0; i < 4; ++i) {
        int e = 4 * t + i;
        abs_off[e] = base;
        if (i == 0 && (t & 127) == 0) bucket_base[t >> 7] = base;
        base += v[i];
    }
    if (t == 1023) bucket_base[NPART] = N_EDGES;
}

// ---------------------------------------------------------------------------
// scatterP: each chunk-block re-reads its edge chunk, claims slots in its
// private per-bucket slice via LDS cursors, writes dst->db / src->sb.
// Each line written by exactly one block -> ~1x writes.
// ---------------------------------------------------------------------------
__global__ void scatterP_kernel(const int* __restrict__ src, const int* __restrict__ dst,
                                const int* __restrict__ abs_off,
                                int* __restrict__ db, int* __restrict__ sb) {
    __shared__ int lcur[NPART];
    if (threadIdx.x < NPART)
        lcur[threadIdx.x] = abs_off[threadIdx.x * NB_RP + blockIdx.x];
    __syncthreads();

    int e4lo = blockIdx.x * CHUNK_E4;
    int e4hi = e4lo + CHUNK_E4; if (e4hi > N_EDGES / 4) e4hi = N_EDGES / 4;

    for (int e4 = e4lo + threadIdx.x; e4 < e4hi; e4 += 256) {
        v4i d = ((const v4i*)dst)[e4];
        v4i s = ((const v4i*)src)[e4];
#define PUT1(DD, SS)                                                          \
        {                                                                     \
            unsigned p = (unsigned)(DD) / NODES_PER_PART;                     \
            int pos = atomicAdd(&lcur[p], 1);                                 \
            db[pos] = (DD); sb[pos] = (SS);                                   \
        }
        PUT1(d.x, s.x) PUT1(d.y, s.y) PUT1(d.z, s.z) PUT1(d.w, s.w)
#undef PUT1
    }
}

// ---------------------------------------------------------------------------
// count_local: partition p (blockIdx&7 -> XCD p) histograms ONLY bucket p's
// dst slice -> cnt atomics are XCD-local, no cross-XCD line ping-pong.
// ---------------------------------------------------------------------------
__global__ void count_local_kernel(const int* __restrict__ db,
                                   const int* __restrict__ bucket_base,
                                   int* __restrict__ cnt) {
    int part = blockIdx.x & (NPART - 1);
    int q = blockIdx.x >> 3;
    int lo = bucket_base[part], hi = bucket_base[part + 1];
    for (int i = lo + q * 256 + threadIdx.x; i < hi; i += PARTBLK * 256) {
        atomicAdd(&cnt[db[i]], 1);
    }
}

__global__ void reduce_kernel(const int* __restrict__ cnt, int* __restrict__ bsum) {
    __shared__ int sd[256];
    int t = threadIdx.x;
    int idx = blockIdx.x * 256 + t;
    sd[t] = (idx < N_NODES) ? cnt[idx] : 0;
    __syncthreads();
    for (int off = 128; off > 0; off >>= 1) {
        if (t < off) sd[t] += sd[t + off];
        __syncthreads();
    }
    if (t == 0) bsum[blockIdx.x] = sd[0];
}

__global__ void scan_bsum_kernel(const int* __restrict__ bsum, int* __restrict__ boff,
                                 int* __restrict__ row_start) {
    __shared__ int sd[256];
    int t = threadIdx.x;
    int v = (t < NBLK_SCAN) ? bsum[t] : 0;
    sd[t] = v;
    __syncthreads();
    for (int off = 1; off < 256; off <<= 1) {
        int u = (t >= off) ? sd[t - off] : 0;
        __syncthreads();
        sd[t] += u;
        __syncthreads();
    }
    if (t < NBLK_SCAN) boff[t] = sd[t] - v;
    if (t == 0) row_start[N_NODES] = N_EDGES;
}

__global__ void scan_write_kernel(const int* __restrict__ cnt, const int* __restrict__ boff,
                                  int* __restrict__ row_start, int* __restrict__ cursor) {
    __shared__ int sd[256];
    int t = threadIdx.x;
    int idx = blockIdx.x * 256 + t;
    int v = (idx < N_NODES) ? cnt[idx] : 0;
    sd[t] = v;
    __syncthreads();
    for (int off = 1; off < 256; off <<= 1) {
        int u = (t >= off) ? sd[t - off] : 0;
        __syncthreads();
        sd[t] += u;
        __syncthreads();
    }
    if (idx < N_NODES) {
        int rs = sd[t] - v + boff[blockIdx.x];
        row_start[idx] = rs;
        cursor[idx] = rs;
    }
}

// ---------------------------------------------------------------------------
// fill_local: partition p consumes ONLY bucket p (coalesced db/sb read) and
// writes its 500 KB csr slice + cursors — all resident in one L2.
// ---------------------------------------------------------------------------
__global__ void fill_local_kernel(const int* __restrict__ db, const int* __restrict__ sb,
                                  const int* __restrict__ bucket_base,
                                  int* __restrict__ cursor, int* __restrict__ csr) {
    int part = blockIdx.x & (NPART - 1);
    int q = blockIdx.x >> 3;
    int lo = bucket_base[part], hi = bucket_base[part + 1];
    for (int i = lo + q * 256 + threadIdx.x; i < hi; i += PARTBLK * 256) {
        int d = db[i];
        int s = sb[i];
        csr[atomicAdd(&cursor[d], 1)] = s;
    }
}

// ---------------------------------------------------------------------------
// x (fp32) -> bf16
// ---------------------------------------------------------------------------
__global__ void xcvt_kernel(const float* __restrict__ x, unsigned short* __restrict__ xb) {
    int i = blockIdx.x * 256 + threadIdx.x;
    if (i >= N_NODES * DIM / 4) return;
    float4 v = ((const float4*)x)[i];
    ushort4 u;
    u.x = f2b(v.x); u.y = f2b(v.y); u.z = f2b(v.z); u.w = f2b(v.w);
    ((ushort4*)xb)[i] = u;
}

// ---------------------------------------------------------------------------
// Pre-pack B = [Wl;Wr] (128x64 fp32) into per-lane MFMA fragments, bf16.
// Consistent k-relabeling between A and B cancels in the MFMA sum over k.
// ---------------------------------------------------------------------------
__global__ void prep_b_kernel(const float* __restrict__ W1l, const float* __restrict__ W1r,
                              const float* __restrict__ W2l, const float* __restrict__ W2r,
                              unsigned short* __restrict__ Bf) {
    int t = blockIdx.x * 256 + threadIdx.x;
    if (t >= 2048) return;
    int layer = t >> 10;
    int rem = t & 1023;
    int ks = rem >> 8;
    int nt = (rem >> 6) & 3;
    int lane = rem & 63;
    int gq = lane >> 4;
    int col = nt * 16 + (lane & 15);
    const float* Wl = layer ? W2l : W1l;
    const float* Wr = layer ? W2r : W1r;
    unsigned short* o = Bf + (size_t)layer * B_STRIDE + ((ks * 4 + nt) * 64 + lane) * 8;
    #pragma unroll
    for (int i = 0; i < 8; ++i) {
        int k = ks * 32 + gq * 8 + i;
        float v = (k < DIM) ? Wl[k * DIM + col] : Wr[(k - DIM) * DIM + col];
        o[i] = f2b(v);
    }
}

// ---------------------------------------------------------------------------
// Neighbor-mean gather, bf16 features (128 B/row). One wave per node;
// 4 groups x 16 lanes; fp32 accumulate, shfl_xor reduce, bf16 write.
// ---------------------------------------------------------------------------
__global__ __launch_bounds__(256) void mean_b_kernel(const unsigned short* __restrict__ feat,
                                                     const int* __restrict__ row_start,
                                                     const int* __restrict__ csr,
                                                     unsigned short* __restrict__ mean) {
    int wv = (blockIdx.x * blockDim.x + threadIdx.x) >> 6;
    if (wv >= N_NODES) return;
    int lane = threadIdx.x & 63;
    int grp = lane >> 4;
    int fi = lane & 15;
    int rs = row_start[wv], re = row_start[wv + 1];

    float4 a0 = make_float4(0.f, 0.f, 0.f, 0.f);
    float4 a1 = make_float4(0.f, 0.f, 0.f, 0.f);
    int i = rs;
    for (; i + 8 <= re; i += 8) {
        int s0 = csr[i + grp];
        int s1 = csr[i + 4 + grp];
        ushort4 u0 = ((const ushort4*)(feat + (size_t)s0 * DIM))[fi];
        ushort4 u1 = ((const ushort4*)(feat + (size_t)s1 * DIM))[fi];
        a0.x += b2f(u0.x); a0.y += b2f(u0.y); a0.z += b2f(u0.z); a0.w += b2f(u0.w);
        a1.x += b2f(u1.x); a1.y += b2f(u1.y); a1.z += b2f(u1.z); a1.w += b2f(u1.w);
    }
    if (i + 4 <= re) {
        int s = csr[i + grp];
        ushort4 u = ((const ushort4*)(feat + (size_t)s * DIM))[fi];
        a0.x += b2f(u.x); a0.y += b2f(u.y); a0.z += b2f(u.z); a0.w += b2f(u.w);
        i += 4;
    }
    if (i + grp < re) {
        int s = csr[i + grp];
        ushort4 u = ((const ushort4*)(feat + (size_t)s * DIM))[fi];
        a1.x += b2f(u.x); a1.y += b2f(u.y); a1.z += b2f(u.z); a1.w += b2f(u.w);
    }
    float4 acc = make_float4(a0.x + a1.x, a0.y + a1.y, a0.z + a1.z, a0.w + a1.w);

    acc.x += __shfl_xor(acc.x, 16); acc.y += __shfl_xor(acc.y, 16);
    acc.z += __shfl_xor(acc.z, 16); acc.w += __shfl_xor(acc.w, 16);
    acc.x += __shfl_xor(acc.x, 32); acc.y += __shfl_xor(acc.y, 32);
    acc.z += __shfl_xor(acc.z, 32); acc.w += __shfl_xor(acc.w, 32);

    if (grp == 0) {
        float inv = 1.0f / fmaxf((float)(re - rs), 1.0f);
        ushort4 m;
        m.x = f2b(acc.x * inv); m.y = f2b(acc.y * inv);
        m.z = f2b(acc.z * inv); m.w = f2b(acc.w * inv);
        ((ushort4*)(mean + (size_t)wv * DIM))[fi] = m;
    }
}

// ---------------------------------------------------------------------------
// MFMA update: C[50000x64] = [mean|x] (bf16, K=128) @ Bf + bias, ReLU, bf16.
// ---------------------------------------------------------------------------
__global__ __launch_bounds__(256, 2) void gemm_kernel(
        const unsigned short* __restrict__ Am,   // K 0..63   (mean)
        const unsigned short* __restrict__ Ax,   // K 64..127 (x or h)
        const unsigned short* __restrict__ Bf,   // packed fragments
        const float* __restrict__ bias,
        unsigned short* __restrict__ outb) {
    int wv = (blockIdx.x * blockDim.x + threadIdx.x) >> 6;
    int n0 = wv * 16;
    if (n0 >= N_NODES) return;
    int lane = threadIdx.x & 63;
    int g = lane >> 4;
    int r = lane & 15;

    const short8* Bv = (const short8*)Bf;
    short8 b00 = Bv[ 0 * 64 + lane], b01 = Bv[ 1 * 64 + lane],
           b02 = Bv[ 2 * 64 + lane], b03 = Bv[ 3 * 64 + lane];
    short8 b10 = Bv[ 4 * 64 + lane], b11 = Bv[ 5 * 64 + lane],
           b12 = Bv[ 6 * 64 + lane], b13 = Bv[ 7 * 64 + lane];
    short8 b20 = Bv[ 8 * 64 + lane], b21 = Bv[ 9 * 64 + lane],
           b22 = Bv[10 * 64 + lane], b23 = Bv[11 * 64 + lane];
    short8 b30 = Bv[12 * 64 + lane], b31 = Bv[13 * 64 + lane],
           b32 = Bv[14 * 64 + lane], b33 = Bv[15 * 64 + lane];

    f32x4 acc0 = {0.f, 0.f, 0.f, 0.f}, acc1 = {0.f, 0.f, 0.f, 0.f};
    f32x4 acc2 = {0.f, 0.f, 0.f, 0.f}, acc3 = {0.f, 0.f, 0.f, 0.f};

    const unsigned short* a1p = Am + (size_t)(n0 + r) * DIM + g * 8;
    const unsigned short* a2p = Ax + (size_t)(n0 + r) * DIM + g * 8;

    short8 a;
    a = *(const short8*)(a1p);          // ks=0: k 0..31
    acc0 = __builtin_amdgcn_mfma_f32_16x16x32_bf16(a, b00, acc0, 0, 0, 0);
    acc1 = __builtin_amdgcn_mfma_f32_16x16x32_bf16(a, b01, acc1, 0, 0, 0);
    acc2 = __builtin_amdgcn_mfma_f32_16x16x32_bf16(a, b02, acc2, 0, 0, 0);
    acc3 = __builtin_amdgcn_mfma_f32_16x16x32_bf16(a, b03, acc3, 0, 0, 0);
    a = *(const short8*)(a1p + 32);     // ks=1: k 32..63
    acc0 = __builtin_amdgcn_mfma_f32_16x16x32_bf16(a, b10, acc0, 0, 0, 0);
    acc1 = __builtin_amdgcn_mfma_f32_16x16x32_bf16(a, b11, acc1, 0, 0, 0);
    acc2 = __builtin_amdgcn_mfma_f32_16x16x32_bf16(a, b12, acc2, 0, 0, 0);
    acc3 = __builtin_amdgcn_mfma_f32_16x16x32_bf16(a, b13, acc3, 0, 0, 0);
    a = *(const short8*)(a2p);          // ks=2: k 64..95
    acc0 = __builtin_amdgcn_mfma_f32_16x16x32_bf16(a, b20, acc0, 0, 0, 0);
    acc1 = __builtin_amdgcn_mfma_f32_16x16x32_bf16(a, b21, acc1, 0, 0, 0);
    acc2 = __builtin_amdgcn_mfma_f32_16x16x32_bf16(a, b22, acc2, 0, 0, 0);
    acc3 = __builtin_amdgcn_mfma_f32_16x16x32_bf16(a, b23, acc3, 0, 0, 0);
    a = *(const short8*)(a2p + 32);     // ks=3: k 96..127
    acc0 = __builtin_amdgcn_mfma_f32_16x16x32_bf16(a, b30, acc0, 0, 0, 0);
    acc1 = __builtin_amdgcn_mfma_f32_16x16x32_bf16(a, b31, acc1, 0, 0, 0);
    acc2 = __builtin_amdgcn_mfma_f32_16x16x32_bf16(a, b32, acc2, 0, 0, 0);
    acc3 = __builtin_amdgcn_mfma_f32_16x16x32_bf16(a, b33, acc3, 0, 0, 0);

    int base_row = n0 + 4 * g;
#define EPI(NT, ACC)                                                          \
    {                                                                         \
        float bc = bias[(NT) * 16 + r];                                       \
        _Pragma("unroll")                                                     \
        for (int i = 0; i < 4; ++i) {                                         \
            float v = fmaxf(ACC[i] + bc, 0.0f);                               \
            outb[(size_t)(base_row + i) * DIM + (NT) * 16 + r] = f2b(v);      \
        }                                                                     \
    }
    EPI(0, acc0) EPI(1, acc1) EPI(2, acc2) EPI(3, acc3)
#undef EPI
}

// ---------------------------------------------------------------------------
// Global mean pool — segmented register reduction over bf16 h2 (batch sorted)
// ---------------------------------------------------------------------------
__global__ void pool_b_kernel(const unsigned short* __restrict__ h,
                              const int* __restrict__ batch,
                              float* __restrict__ psum, float* __restrict__ pcnt) {
    int wv = (blockIdx.x * blockDim.x + threadIdx.x) >> 6;
    int start = wv * 16;
    if (start >= N_NODES) return;
    int j = threadIdx.x & 63;
    int end = start + 16;
    if (end > N_NODES) end = N_NODES;

    int g = batch[start];
    float acc = 0.0f, cnt = 0.0f;
    for (int n = start; n < end; ++n) {
        int gn = batch[n];
        if (gn != g) {
            atomicAdd(&psum[g * DIM + j], acc);
            if (j == 0) atomicAdd(&pcnt[g], cnt);
            g = gn; acc = 0.0f; cnt = 0.0f;
        }
        acc += b2f(h[(size_t)n * DIM + j]);
        cnt += 1.0f;
    }
    atomicAdd(&psum[g * DIM + j], acc);
    if (j == 0) atomicAdd(&pcnt[g], cnt);
}

// ---------------------------------------------------------------------------
// Final FC: out[g][o] = (psum[g]/max(cnt,1)) @ Wfc + bfc   (64 x 8, fp32)
// ---------------------------------------------------------------------------
__global__ void fc_kernel(const float* __restrict__ psum,
                          const float* __restrict__ pcnt,
                          const float* __restrict__ Wfc,
                          const float* __restrict__ bfc,
                          float* __restrict__ out) {
    int tid = threadIdx.x;
    if (tid >= N_GRAPHS * OUT_DIM) return;
    int g = tid >> 3;
    int o = tid & 7;
    float inv = 1.0f / fmaxf(pcnt[g], 1.0f);
    float s = bfc[o];
    #pragma unroll
    for (int k = 0; k < DIM; ++k) {
        s += psum[g * DIM + k] * inv * Wfc[k * OUT_DIM + o];
    }
    out[g * OUT_DIM + o] = s;
}

extern "C" void kernel_launch(void* const* d_in, const int* in_sizes, int n_in,
                              void* d_out, int out_size, void* d_ws, size_t ws_size,
                              hipStream_t stream) {
    const float* x   = (const float*)d_in[0];
    const int* ei    = (const int*)d_in[1];
    const int* batch = (const int*)d_in[2];
    const float* W1l = (const float*)d_in[3];
    const float* b1  = (const float*)d_in[4];
    const float* W1r = (const float*)d_in[5];
    const float* W2l = (const float*)d_in[6];
    const float* b2  = (const float*)d_in[7];
    const float* W2r = (const float*)d_in[8];
    const float* Wfc = (const float*)d_in[9];
    const float* bfc = (const float*)d_in[10];
    float* out = (float*)d_out;

    const int* src = ei;
    const int* dst = ei + N_EDGES;

    // workspace layout (~38.3 MB)
    const size_t SZ_BF   = (size_t)N_NODES * DIM * 2;              // 6.4 MB
    const size_t SZ_CSR  = (size_t)N_EDGES * sizeof(int);          // 4 MB
    const size_t SZ_CNT  = ((size_t)(N_NODES + 1) * sizeof(int) + 255) & ~(size_t)255;
    char* ws = (char*)d_ws;
    unsigned short* xb    = (unsigned short*)(ws);
    unsigned short* meanb = (unsigned short*)(ws + SZ_BF);
    unsigned short* h1b   = (unsigned short*)(ws + 2 * SZ_BF);
    unsigned short* h2b   = (unsigned short*)(ws + 3 * SZ_BF);
    int*   db        = (int*)(ws + 4 * SZ_BF);                     // 4 MB (bucketed dst)
    int*   sb        = (int*)(ws + 4 * SZ_BF + SZ_CSR);            // 4 MB (bucketed src)
    int*   csr       = (int*)(ws + 4 * SZ_BF + 2 * SZ_CSR);
    int*   cnt       = (int*)(ws + 4 * SZ_BF + 3 * SZ_CSR);
    int*   row_start = (int*)(ws + 4 * SZ_BF + 3 * SZ_CSR + SZ_CNT);
    int*   cursor    = (int*)(ws + 4 * SZ_BF + 3 * SZ_CSR + 2 * SZ_CNT);
    char*  tail      = ws + 4 * SZ_BF + 3 * SZ_CSR + 3 * SZ_CNT;
    int*   bsum      = (int*)(tail);                 // 256 ints
    int*   boff      = bsum + 256;                   // 256 ints
    int*   blockcnt  = boff + 256;                   // 512*8 ints = 16 KB
    int*   abs_off   = blockcnt + NB_RP * NPART;     // 4096 ints = 16 KB
    int*   bucket_base = abs_off + NB_RP * NPART;    // 9 ints
    unsigned short* Bf = (unsigned short*)(bucket_base + 16);      // 32 KB
    float* psum      = (float*)((char*)Bf + 2 * B_STRIDE * 2);
    float* pcnt      = psum + N_GRAPHS * DIM;

    const int meanBlocks  = (N_NODES + 3) / 4;                     // 12500
    const int tileWaves   = (N_NODES + 15) / 16;                   // 3125
    const int tileBlocks  = (tileWaves + 3) / 4;                   // 782
    const int xcvtBlocks  = (N_NODES * DIM / 4 + 255) / 256;       // 3125

    hipMemsetAsync(cnt, 0, (size_t)N_NODES * sizeof(int), stream);
    hipMemsetAsync(psum, 0, (size_t)(N_GRAPHS * DIM + N_GRAPHS) * sizeof(float), stream);

    // ---- CSR build (bucketed; all heavy atomics XCD-local) ----
    histB_kernel<<<NB_RP, 256, 0, stream>>>(dst, blockcnt);
    scan8_kernel<<<1, 1024, 0, stream>>>(blockcnt, abs_off, bucket_base);
    scatterP_kernel<<<NB_RP, 256, 0, stream>>>(src, dst, abs_off, db, sb);
    count_local_kernel<<<NPART * PARTBLK, 256, 0, stream>>>(db, bucket_base, cnt);
    reduce_kernel<<<NBLK_SCAN, 256, 0, stream>>>(cnt, bsum);
    scan_bsum_kernel<<<1, 256, 0, stream>>>(bsum, boff, row_start);
    scan_write_kernel<<<NBLK_SCAN, 256, 0, stream>>>(cnt, boff, row_start, cursor);
    fill_local_kernel<<<NPART * PARTBLK, 256, 0, stream>>>(db, sb, bucket_base, cursor, csr);

    // ---- bf16 conversions / weight pre-pack ----
    xcvt_kernel<<<xcvtBlocks, 256, 0, stream>>>(x, xb);
    prep_b_kernel<<<8, 256, 0, stream>>>(W1l, W1r, W2l, W2r, Bf);

    // ---- Layer 1 ----
    mean_b_kernel<<<meanBlocks, 256, 0, stream>>>(xb, row_start, csr, meanb);
    gemm_kernel<<<tileBlocks, 256, 0, stream>>>(meanb, xb, Bf, b1, h1b);
    // ---- Layer 2 ----
    mean_b_kernel<<<meanBlocks, 256, 0, stream>>>(h1b, row_start, csr, meanb);
    gemm_kernel<<<tileBlocks, 256, 0, stream>>>(meanb, h1b, Bf + B_STRIDE, b2, h2b);
    // ---- Pool + FC ----
    pool_b_kernel<<<tileBlocks, 256, 0, stream>>>(h2b, batch, psum, pcnt);
    fc_kernel<<<1, 512, 0, stream>>>(psum, pcnt, Wfc, bfc, out);
}

// Round 12
// 162.886 us; speedup vs baseline: 1.3277x; 1.3277x over previous
//
#include <hip/hip_runtime.h>
#include <hip/hip_bf16.h>

#define N_NODES 50000
#define N_EDGES 1000000
#define DIM 64
#define N_GRAPHS 64
#define OUT_DIM 8
#define NBLK_SCAN 196         // ceil(50000/256)
#define NPART 8               // one dst-range partition per XCD
#define SUBBLK 16             // blocks per partition (count_priv / fill_det)
#define NODES_PER_PART (N_NODES / NPART)   // 6250
#define NB_RP 512             // chunked radix-partition blocks
#define CHUNK_E4 489          // ceil(250000/512)
#define B_STRIDE 8192         // bf16 elements per packed weight layer (128x64)
#define POOL_NPW 64           // pool: nodes per wave

typedef __attribute__((ext_vector_type(8))) short short8;   // 8 bf16 = 4 VGPR
typedef __attribute__((ext_vector_type(4))) float f32x4;    // MFMA C/D
typedef __attribute__((ext_vector_type(4))) int v4i;

__device__ __forceinline__ unsigned short f2b(float f) {
    __hip_bfloat16 h = __float2bfloat16(f);
    return *reinterpret_cast<unsigned short*>(&h);
}
__device__ __forceinline__ float b2f(unsigned short u) {
    __hip_bfloat16 h = *reinterpret_cast<__hip_bfloat16*>(&u);
    return __bfloat162float(h);
}

// ---------------------------------------------------------------------------
// histB: per-chunk 8-bucket counts only (VGPR if-chain + shfl reduce).
// ---------------------------------------------------------------------------
__global__ void histB_kernel(const int* __restrict__ dst, int* __restrict__ blockcnt) {
    __shared__ int sc[NPART];
    if (threadIdx.x < NPART) sc[threadIdx.x] = 0;
    __syncthreads();

    int e4lo = blockIdx.x * CHUNK_E4;
    int e4hi = e4lo + CHUNK_E4; if (e4hi > N_EDGES / 4) e4hi = N_EDGES / 4;

    int c0 = 0, c1 = 0, c2 = 0, c3 = 0, c4 = 0, c5 = 0, c6 = 0, c7 = 0;
    for (int e4 = e4lo + threadIdx.x; e4 < e4hi; e4 += 256) {
        v4i d = ((const v4i*)dst)[e4];
#define CNT1(DD)                                                              \
        {                                                                     \
            unsigned p = (unsigned)(DD) / NODES_PER_PART;                     \
            c0 += (p == 0); c1 += (p == 1); c2 += (p == 2); c3 += (p == 3);   \
            c4 += (p == 4); c5 += (p == 5); c6 += (p == 6); c7 += (p == 7);   \
        }
        CNT1(d.x) CNT1(d.y) CNT1(d.z) CNT1(d.w)
#undef CNT1
    }
    #pragma unroll
    for (int off = 32; off > 0; off >>= 1) {
        c0 += __shfl_xor(c0, off); c1 += __shfl_xor(c1, off);
        c2 += __shfl_xor(c2, off); c3 += __shfl_xor(c3, off);
        c4 += __shfl_xor(c4, off); c5 += __shfl_xor(c5, off);
        c6 += __shfl_xor(c6, off); c7 += __shfl_xor(c7, off);
    }
    if ((threadIdx.x & 63) == 0) {
        atomicAdd(&sc[0], c0); atomicAdd(&sc[1], c1);
        atomicAdd(&sc[2], c2); atomicAdd(&sc[3], c3);
        atomicAdd(&sc[4], c4); atomicAdd(&sc[5], c5);
        atomicAdd(&sc[6], c6); atomicAdd(&sc[7], c7);
    }
    __syncthreads();
    if (threadIdx.x < NPART) blockcnt[blockIdx.x * NPART + threadIdx.x] = sc[threadIdx.x];
}

// ---------------------------------------------------------------------------
// scan8: exclusive scan over blockcnt, bucket-major (e = p*NB_RP + b).
// ---------------------------------------------------------------------------
__global__ void scan8_kernel(const int* __restrict__ blockcnt,
                             int* __restrict__ abs_off, int* __restrict__ bucket_base) {
    __shared__ int part[1024];
    int t = threadIdx.x;
    int v[4], s = 0;
    #pragma unroll
    for (int i = 0; i < 4; ++i) {
        int e = 4 * t + i;
        int p = e >> 9, b = e & (NB_RP - 1);
        v[i] = blockcnt[b * NPART + p];
        s += v[i];
    }
    part[t] = s;
    __syncthreads();
    for (int off = 1; off < 1024; off <<= 1) {
        int u = (t >= off) ? part[t - off] : 0;
        __syncthreads();
        part[t] += u;
        __syncthreads();
    }
    int base = (t == 0) ? 0 : part[t - 1];
    #pragma unroll
    for (int i = 0; i < 4; ++i) {
        int e = 4 * t + i;
        abs_off[e] = base;
        if (i == 0 && (t & 127) == 0) bucket_base[t >> 7] = base;
        base += v[i];
    }
    if (t == 1023) bucket_base[NPART] = N_EDGES;
}

// ---------------------------------------------------------------------------
// scatterP: chunk-block claims per-bucket slots via LDS cursors, writes db/sb.
// ---------------------------------------------------------------------------
__global__ void scatterP_kernel(const int* __restrict__ src, const int* __restrict__ dst,
                                const int* __restrict__ abs_off,
                                int* __restrict__ db, int* __restrict__ sb) {
    __shared__ int lcur[NPART];
    if (threadIdx.x < NPART)
        lcur[threadIdx.x] = abs_off[threadIdx.x * NB_RP + blockIdx.x];
    __syncthreads();

    int e4lo = blockIdx.x * CHUNK_E4;
    int e4hi = e4lo + CHUNK_E4; if (e4hi > N_EDGES / 4) e4hi = N_EDGES / 4;

    for (int e4 = e4lo + threadIdx.x; e4 < e4hi; e4 += 256) {
        v4i d = ((const v4i*)dst)[e4];
        v4i s = ((const v4i*)src)[e4];
#define PUT1(DD, SS)                                                          \
        {                                                                     \
            unsigned p = (unsigned)(DD) / NODES_PER_PART;                     \
            int pos = atomicAdd(&lcur[p], 1);                                 \
            db[pos] = (DD); sb[pos] = (SS);                                   \
        }
        PUT1(d.x, s.x) PUT1(d.y, s.y) PUT1(d.z, s.z) PUT1(d.w, s.w)
#undef PUT1
    }
}

// ---------------------------------------------------------------------------
// count_priv: block (p,sub) LDS-histograms its contiguous sub-range of
// bucket p, writes private histogram non-atomically. ZERO global atomics —
// R10/R11 showed scattered global atomicAdd costs ~30 B HBM write each.
// ---------------------------------------------------------------------------
__global__ void count_priv_kernel(const int* __restrict__ db,
                                  const int* __restrict__ bucket_base,
                                  int* __restrict__ privhist) {
    __shared__ int lh[NODES_PER_PART];
    int p = blockIdx.x & (NPART - 1);
    int sub = blockIdx.x >> 3;
    for (int i = threadIdx.x; i < NODES_PER_PART; i += 256) lh[i] = 0;
    __syncthreads();

    int lo = bucket_base[p], hi = bucket_base[p + 1];
    int len = hi - lo;
    int chunk = (len + SUBBLK - 1) / SUBBLK;
    int clo = lo + sub * chunk;
    int chi = clo + chunk; if (chi > hi) chi = hi;
    int nbase = p * NODES_PER_PART;

    for (int i = clo + threadIdx.x; i < chi; i += 256)
        atomicAdd(&lh[db[i] - nbase], 1);
    __syncthreads();

    int* o = privhist + (size_t)blockIdx.x * NODES_PER_PART;  // blk = p*... index by blockIdx
    for (int i = threadIdx.x; i < NODES_PER_PART; i += 256) o[i] = lh[i];
}

// ---------------------------------------------------------------------------
// merge_hist: cnt[n] = sum over the partition's 16 private histograms;
// rewrite privhist in place as exclusive prefixes (for fill_det).
// ---------------------------------------------------------------------------
__global__ void merge_hist_kernel(int* __restrict__ privhist, int* __restrict__ cnt) {
    int n = blockIdx.x * 256 + threadIdx.x;
    if (n >= N_NODES) return;
    int p = n / NODES_PER_PART;
    int nl = n - p * NODES_PER_PART;
    int run = 0;
    #pragma unroll
    for (int b = 0; b < SUBBLK; ++b) {
        size_t idx = (size_t)(b * NPART + p) * NODES_PER_PART + nl; // blockIdx = b*8+p
        int v = privhist[idx];
        privhist[idx] = run;
        run += v;
    }
    cnt[n] = run;
}

__global__ void reduce_kernel(const int* __restrict__ cnt, int* __restrict__ bsum) {
    __shared__ int sd[256];
    int t = threadIdx.x;
    int idx = blockIdx.x * 256 + t;
    sd[t] = (idx < N_NODES) ? cnt[idx] : 0;
    __syncthreads();
    for (int off = 128; off > 0; off >>= 1) {
        if (t < off) sd[t] += sd[t + off];
        __syncthreads();
    }
    if (t == 0) bsum[blockIdx.x] = sd[0];
}

__global__ void scan_bsum_kernel(const int* __restrict__ bsum, int* __restrict__ boff,
                                 int* __restrict__ row_start) {
    __shared__ int sd[256];
    int t = threadIdx.x;
    int v = (t < NBLK_SCAN) ? bsum[t] : 0;
    sd[t] = v;
    __syncthreads();
    for (int off = 1; off < 256; off <<= 1) {
        int u = (t >= off) ? sd[t - off] : 0;
        __syncthreads();
        sd[t] += u;
        __syncthreads();
    }
    if (t < NBLK_SCAN) boff[t] = sd[t] - v;
    if (t == 0) row_start[N_NODES] = N_EDGES;
}

__global__ void scan_write_kernel(const int* __restrict__ cnt, const int* __restrict__ boff,
                                  int* __restrict__ row_start) {
    __shared__ int sd[256];
    int t = threadIdx.x;
    int idx = blockIdx.x * 256 + t;
    int v = (idx < N_NODES) ? cnt[idx] : 0;
    sd[t] = v;
    __syncthreads();
    for (int off = 1; off < 256; off <<= 1) {
        int u = (t >= off) ? sd[t - off] : 0;
        __syncthreads();
        sd[t] += u;
        __syncthreads();
    }
    if (idx < N_NODES) row_start[idx] = sd[t] - v + boff[blockIdx.x];
}

// ---------------------------------------------------------------------------
// fill_det: block (p,sub) seeds LDS cursors = row_start + exclusive prefix,
// re-reads ITS db/sb sub-range, claims slots via LDS atomics, writes csr.
// No global atomics; each csr slot written exactly once.
// ---------------------------------------------------------------------------
__global__ void fill_det_kernel(const int* __restrict__ db, const int* __restrict__ sb,
                                const int* __restrict__ bucket_base,
                                const int* __restrict__ row_start,
                                const int* __restrict__ privhist,
                                int* __restrict__ csr) {
    __shared__ int cur[NODES_PER_PART];
    int p = blockIdx.x & (NPART - 1);
    int sub = blockIdx.x >> 3;
    int nbase = p * NODES_PER_PART;
    const int* ph = privhist + (size_t)blockIdx.x * NODES_PER_PART;
    for (int i = threadIdx.x; i < NODES_PER_PART; i += 256)
        cur[i] = row_start[nbase + i] + ph[i];
    __syncthreads();

    int lo = bucket_base[p], hi = bucket_base[p + 1];
    int len = hi - lo;
    int chunk = (len + SUBBLK - 1) / SUBBLK;
    int clo = lo + sub * chunk;
    int chi = clo + chunk; if (chi > hi) chi = hi;

    for (int i = clo + threadIdx.x; i < chi; i += 256) {
        int d = db[i];
        int s = sb[i];
        int pos = atomicAdd(&cur[d - nbase], 1);
        csr[pos] = s;
    }
}

// ---------------------------------------------------------------------------
// x (fp32) -> bf16
// ---------------------------------------------------------------------------
__global__ void xcvt_kernel(const float* __restrict__ x, unsigned short* __restrict__ xb) {
    int i = blockIdx.x * 256 + threadIdx.x;
    if (i >= N_NODES * DIM / 4) return;
    float4 v = ((const float4*)x)[i];
    ushort4 u;
    u.x = f2b(v.x); u.y = f2b(v.y); u.z = f2b(v.z); u.w = f2b(v.w);
    ((ushort4*)xb)[i] = u;
}

// ---------------------------------------------------------------------------
// Pre-pack B = [Wl;Wr] into per-lane MFMA fragments, bf16 (consistent k-map).
// ---------------------------------------------------------------------------
__global__ void prep_b_kernel(const float* __restrict__ W1l, const float* __restrict__ W1r,
                              const float* __restrict__ W2l, const float* __restrict__ W2r,
                              unsigned short* __restrict__ Bf) {
    int t = blockIdx.x * 256 + threadIdx.x;
    if (t >= 2048) return;
    int layer = t >> 10;
    int rem = t & 1023;
    int ks = rem >> 8;
    int nt = (rem >> 6) & 3;
    int lane = rem & 63;
    int gq = lane >> 4;
    int col = nt * 16 + (lane & 15);
    const float* Wl = layer ? W2l : W1l;
    const float* Wr = layer ? W2r : W1r;
    unsigned short* o = Bf + (size_t)layer * B_STRIDE + ((ks * 4 + nt) * 64 + lane) * 8;
    #pragma unroll
    for (int i = 0; i < 8; ++i) {
        int k = ks * 32 + gq * 8 + i;
        float v = (k < DIM) ? Wl[k * DIM + col] : Wr[(k - DIM) * DIM + col];
        o[i] = f2b(v);
    }
}

// ---------------------------------------------------------------------------
// Neighbor-mean gather, bf16 features (128 B/row).
// ---------------------------------------------------------------------------
__global__ __launch_bounds__(256) void mean_b_kernel(const unsigned short* __restrict__ feat,
                                                     const int* __restrict__ row_start,
                                                     const int* __restrict__ csr,
                                                     unsigned short* __restrict__ mean) {
    int wv = (blockIdx.x * blockDim.x + threadIdx.x) >> 6;
    if (wv >= N_NODES) return;
    int lane = threadIdx.x & 63;
    int grp = lane >> 4;
    int fi = lane & 15;
    int rs = row_start[wv], re = row_start[wv + 1];

    float4 a0 = make_float4(0.f, 0.f, 0.f, 0.f);
    float4 a1 = make_float4(0.f, 0.f, 0.f, 0.f);
    int i = rs;
    for (; i + 8 <= re; i += 8) {
        int s0 = csr[i + grp];
        int s1 = csr[i + 4 + grp];
        ushort4 u0 = ((const ushort4*)(feat + (size_t)s0 * DIM))[fi];
        ushort4 u1 = ((const ushort4*)(feat + (size_t)s1 * DIM))[fi];
        a0.x += b2f(u0.x); a0.y += b2f(u0.y); a0.z += b2f(u0.z); a0.w += b2f(u0.w);
        a1.x += b2f(u1.x); a1.y += b2f(u1.y); a1.z += b2f(u1.z); a1.w += b2f(u1.w);
    }
    if (i + 4 <= re) {
        int s = csr[i + grp];
        ushort4 u = ((const ushort4*)(feat + (size_t)s * DIM))[fi];
        a0.x += b2f(u.x); a0.y += b2f(u.y); a0.z += b2f(u.z); a0.w += b2f(u.w);
        i += 4;
    }
    if (i + grp < re) {
        int s = csr[i + grp];
        ushort4 u = ((const ushort4*)(feat + (size_t)s * DIM))[fi];
        a1.x += b2f(u.x); a1.y += b2f(u.y); a1.z += b2f(u.z); a1.w += b2f(u.w);
    }
    float4 acc = make_float4(a0.x + a1.x, a0.y + a1.y, a0.z + a1.z, a0.w + a1.w);

    acc.x += __shfl_xor(acc.x, 16); acc.y += __shfl_xor(acc.y, 16);
    acc.z += __shfl_xor(acc.z, 16); acc.w += __shfl_xor(acc.w, 16);
    acc.x += __shfl_xor(acc.x, 32); acc.y += __shfl_xor(acc.y, 32);
    acc.z += __shfl_xor(acc.z, 32); acc.w += __shfl_xor(acc.w, 32);

    if (grp == 0) {
        float inv = 1.0f / fmaxf((float)(re - rs), 1.0f);
        ushort4 m;
        m.x = f2b(acc.x * inv); m.y = f2b(acc.y * inv);
        m.z = f2b(acc.z * inv); m.w = f2b(acc.w * inv);
        ((ushort4*)(mean + (size_t)wv * DIM))[fi] = m;
    }
}

// ---------------------------------------------------------------------------
// MFMA update: C[50000x64] = [mean|x] (bf16, K=128) @ Bf + bias, ReLU, bf16.
// ---------------------------------------------------------------------------
__global__ __launch_bounds__(256, 2) void gemm_kernel(
        const unsigned short* __restrict__ Am,
        const unsigned short* __restrict__ Ax,
        const unsigned short* __restrict__ Bf,
        const float* __restrict__ bias,
        unsigned short* __restrict__ outb) {
    int wv = (blockIdx.x * blockDim.x + threadIdx.x) >> 6;
    int n0 = wv * 16;
    if (n0 >= N_NODES) return;
    int lane = threadIdx.x & 63;
    int g = lane >> 4;
    int r = lane & 15;

    const short8* Bv = (const short8*)Bf;
    short8 b00 = Bv[ 0 * 64 + lane], b01 = Bv[ 1 * 64 + lane],
           b02 = Bv[ 2 * 64 + lane], b03 = Bv[ 3 * 64 + lane];
    short8 b10 = Bv[ 4 * 64 + lane], b11 = Bv[ 5 * 64 + lane],
           b12 = Bv[ 6 * 64 + lane], b13 = Bv[ 7 * 64 + lane];
    short8 b20 = Bv[ 8 * 64 + lane], b21 = Bv[ 9 * 64 + lane],
           b22 = Bv[10 * 64 + lane], b23 = Bv[11 * 64 + lane];
    short8 b30 = Bv[12 * 64 + lane], b31 = Bv[13 * 64 + lane],
           b32 = Bv[14 * 64 + lane], b33 = Bv[15 * 64 + lane];

    f32x4 acc0 = {0.f, 0.f, 0.f, 0.f}, acc1 = {0.f, 0.f, 0.f, 0.f};
    f32x4 acc2 = {0.f, 0.f, 0.f, 0.f}, acc3 = {0.f, 0.f, 0.f, 0.f};

    const unsigned short* a1p = Am + (size_t)(n0 + r) * DIM + g * 8;
    const unsigned short* a2p = Ax + (size_t)(n0 + r) * DIM + g * 8;

    short8 a;
    a = *(const short8*)(a1p);
    acc0 = __builtin_amdgcn_mfma_f32_16x16x32_bf16(a, b00, acc0, 0, 0, 0);
    acc1 = __builtin_amdgcn_mfma_f32_16x16x32_bf16(a, b01, acc1, 0, 0, 0);
    acc2 = __builtin_amdgcn_mfma_f32_16x16x32_bf16(a, b02, acc2, 0, 0, 0);
    acc3 = __builtin_amdgcn_mfma_f32_16x16x32_bf16(a, b03, acc3, 0, 0, 0);
    a = *(const short8*)(a1p + 32);
    acc0 = __builtin_amdgcn_mfma_f32_16x16x32_bf16(a, b10, acc0, 0, 0, 0);
    acc1 = __builtin_amdgcn_mfma_f32_16x16x32_bf16(a, b11, acc1, 0, 0, 0);
    acc2 = __builtin_amdgcn_mfma_f32_16x16x32_bf16(a, b12, acc2, 0, 0, 0);
    acc3 = __builtin_amdgcn_mfma_f32_16x16x32_bf16(a, b13, acc3, 0, 0, 0);
    a = *(const short8*)(a2p);
    acc0 = __builtin_amdgcn_mfma_f32_16x16x32_bf16(a, b20, acc0, 0, 0, 0);
    acc1 = __builtin_amdgcn_mfma_f32_16x16x32_bf16(a, b21, acc1, 0, 0, 0);
    acc2 = __builtin_amdgcn_mfma_f32_16x16x32_bf16(a, b22, acc2, 0, 0, 0);
    acc3 = __builtin_amdgcn_mfma_f32_16x16x32_bf16(a, b23, acc3, 0, 0, 0);
    a = *(const short8*)(a2p + 32);
    acc0 = __builtin_amdgcn_mfma_f32_16x16x32_bf16(a, b30, acc0, 0, 0, 0);
    acc1 = __builtin_amdgcn_mfma_f32_16x16x32_bf16(a, b31, acc1, 0, 0, 0);
    acc2 = __builtin_amdgcn_mfma_f32_16x16x32_bf16(a, b32, acc2, 0, 0, 0);
    acc3 = __builtin_amdgcn_mfma_f32_16x16x32_bf16(a, b33, acc3, 0, 0, 0);

    int base_row = n0 + 4 * g;
#define EPI(NT, ACC)                                                          \
    {                                                                         \
        float bc = bias[(NT) * 16 + r];                                       \
        _Pragma("unroll")                                                     \
        for (int i = 0; i < 4; ++i) {                                         \
            float v = fmaxf(ACC[i] + bc, 0.0f);                               \
            outb[(size_t)(base_row + i) * DIM + (NT) * 16 + r] = f2b(v);      \
        }                                                                     \
    }
    EPI(0, acc0) EPI(1, acc1) EPI(2, acc2) EPI(3, acc3)
#undef EPI
}

// ---------------------------------------------------------------------------
// Global mean pool — 64 nodes/wave segmented reduction (batch sorted).
// ---------------------------------------------------------------------------
__global__ void pool_b_kernel(const unsigned short* __restrict__ h,
                              const int* __restrict__ batch,
                              float* __restrict__ psum, float* __restrict__ pcnt) {
    int wv = (blockIdx.x * blockDim.x + threadIdx.x) >> 6;
    int start = wv * POOL_NPW;
    if (start >= N_NODES) return;
    int j = threadIdx.x & 63;
    int end = start + POOL_NPW;
    if (end > N_NODES) end = N_NODES;

    int g = batch[start];
    float acc = 0.0f, cnt = 0.0f;
    for (int n = start; n < end; ++n) {
        int gn = batch[n];
        if (gn != g) {
            atomicAdd(&psum[g * DIM + j], acc);
            if (j == 0) atomicAdd(&pcnt[g], cnt);
            g = gn; acc = 0.0f; cnt = 0.0f;
        }
        acc += b2f(h[(size_t)n * DIM + j]);
        cnt += 1.0f;
    }
    atomicAdd(&psum[g * DIM + j], acc);
    if (j == 0) atomicAdd(&pcnt[g], cnt);
}

// ---------------------------------------------------------------------------
// Final FC: out[g][o] = (psum[g]/max(cnt,1)) @ Wfc + bfc   (64 x 8, fp32)
// ---------------------------------------------------------------------------
__global__ void fc_kernel(const float* __restrict__ psum,
                          const float* __restrict__ pcnt,
                          const float* __restrict__ Wfc,
                          const float* __restrict__ bfc,
                          float* __restrict__ out) {
    int tid = threadIdx.x;
    if (tid >= N_GRAPHS * OUT_DIM) return;
    int g = tid >> 3;
    int o = tid & 7;
    float inv = 1.0f / fmaxf(pcnt[g], 1.0f);
    float s = bfc[o];
    #pragma unroll
    for (int k = 0; k < DIM; ++k) {
        s += psum[g * DIM + k] * inv * Wfc[k * OUT_DIM + o];
    }
    out[g * OUT_DIM + o] = s;
}

extern "C" void kernel_launch(void* const* d_in, const int* in_sizes, int n_in,
                              void* d_out, int out_size, void* d_ws, size_t ws_size,
                              hipStream_t stream) {
    const float* x   = (const float*)d_in[0];
    const int* ei    = (const int*)d_in[1];
    const int* batch = (const int*)d_in[2];
    const float* W1l = (const float*)d_in[3];
    const float* b1  = (const float*)d_in[4];
    const float* W1r = (const float*)d_in[5];
    const float* W2l = (const float*)d_in[6];
    const float* b2  = (const float*)d_in[7];
    const float* W2r = (const float*)d_in[8];
    const float* Wfc = (const float*)d_in[9];
    const float* bfc = (const float*)d_in[10];
    float* out = (float*)d_out;

    const int* src = ei;
    const int* dst = ei + N_EDGES;

    // ---- workspace layout (~30 MB). Region A is time-shared: during CSR
    // build it holds db/sb/privhist; afterwards the bf16 feature buffers
    // (stream order guarantees build completes before xcvt writes xb). ----
    const size_t SZ_BF   = (size_t)N_NODES * DIM * 2;              // 6.4 MB
    const size_t SZ_CSR  = (size_t)N_EDGES * sizeof(int);          // 4 MB
    const size_t SZ_CNT  = ((size_t)(N_NODES + 1) * sizeof(int) + 255) & ~(size_t)255;
    char* ws = (char*)d_ws;
    int*   csr       = (int*)(ws);
    int*   cnt       = (int*)(ws + SZ_CSR);
    int*   row_start = (int*)(ws + SZ_CSR + SZ_CNT);
    char*  tail      = ws + SZ_CSR + 2 * SZ_CNT;
    int*   bsum      = (int*)(tail);                 // 256 ints
    int*   boff      = bsum + 256;                   // 256 ints
    int*   blockcnt  = boff + 256;                   // 512*8 ints
    int*   abs_off   = blockcnt + NB_RP * NPART;     // 4096 ints
    int*   bucket_base = abs_off + NB_RP * NPART;    // 9 ints
    unsigned short* Bf = (unsigned short*)(bucket_base + 16);      // 32 KB
    float* psum      = (float*)((char*)Bf + 2 * B_STRIDE * 2);
    float* pcnt      = psum + N_GRAPHS * DIM;
    char*  regionA   = (char*)(pcnt + N_GRAPHS) + 4096;
    regionA = (char*)(((size_t)regionA + 255) & ~(size_t)255);
    // build-phase aliases
    int*   db        = (int*)(regionA);                            // 4 MB
    int*   sb        = (int*)(regionA + SZ_CSR);                   // 4 MB
    int*   privhist  = (int*)(regionA + 2 * SZ_CSR);               // 3.2 MB
    // compute-phase aliases
    unsigned short* xb    = (unsigned short*)(regionA);
    unsigned short* meanb = (unsigned short*)(regionA + SZ_BF);
    unsigned short* h1b   = (unsigned short*)(regionA + 2 * SZ_BF);
    unsigned short* h2b   = (unsigned short*)(regionA + 3 * SZ_BF);

    const int meanBlocks  = (N_NODES + 3) / 4;                     // 12500
    const int tileWaves   = (N_NODES + 15) / 16;                   // 3125
    const int tileBlocks  = (tileWaves + 3) / 4;                   // 782
    const int xcvtBlocks  = (N_NODES * DIM / 4 + 255) / 256;       // 3125
    const int poolWaves   = (N_NODES + POOL_NPW - 1) / POOL_NPW;   // 782
    const int poolBlocks  = (poolWaves + 3) / 4;                   // 196

    hipMemsetAsync(psum, 0, (size_t)(N_GRAPHS * DIM + N_GRAPHS) * sizeof(float), stream);

    // ---- CSR build: deterministic two-pass counting sort, no global atomics
    histB_kernel<<<NB_RP, 256, 0, stream>>>(dst, blockcnt);
    scan8_kernel<<<1, 1024, 0, stream>>>(blockcnt, abs_off, bucket_base);
    scatterP_kernel<<<NB_RP, 256, 0, stream>>>(src, dst, abs_off, db, sb);
    count_priv_kernel<<<NPART * SUBBLK, 256, 0, stream>>>(db, bucket_base, privhist);
    merge_hist_kernel<<<NBLK_SCAN, 256, 0, stream>>>(privhist, cnt);
    reduce_kernel<<<NBLK_SCAN, 256, 0, stream>>>(cnt, bsum);
    scan_bsum_kernel<<<1, 256, 0, stream>>>(bsum, boff, row_start);
    scan_write_kernel<<<NBLK_SCAN, 256, 0, stream>>>(cnt, boff, row_start);
    fill_det_kernel<<<NPART * SUBBLK, 256, 0, stream>>>(db, sb, bucket_base, row_start,
                                                        privhist, csr);

    // ---- bf16 conversions / weight pre-pack (regionA switches role here) --
    xcvt_kernel<<<xcvtBlocks, 256, 0, stream>>>(x, xb);
    prep_b_kernel<<<8, 256, 0, stream>>>(W1l, W1r, W2l, W2r, Bf);

    // ---- Layer 1 ----
    mean_b_kernel<<<meanBlocks, 256, 0, stream>>>(xb, row_start, csr, meanb);
    gemm_kernel<<<tileBlocks, 256, 0, stream>>>(meanb, xb, Bf, b1, h1b);
    // ---- Layer 2 ----
    mean_b_kernel<<<meanBlocks, 256, 0, stream>>>(h1b, row_start, csr, meanb);
    gemm_kernel<<<tileBlocks, 256, 0, stream>>>(meanb, h1b, Bf + B_STRIDE, b2, h2b);
    // ---- Pool + FC ----
    pool_b_kernel<<<poolBlocks, 256, 0, stream>>>(h2b, batch, psum, pcnt);
    fc_kernel<<<1, 512, 0, stream>>>(psum, pcnt, Wfc, bfc, out);
}